// Round 11
// baseline (120.780 us; speedup 1.0000x reference)
//
#include <hip/hip_runtime.h>
#include <hip/hip_bf16.h>
#include <math.h>

#define D 256
#define INV_TAU 20.0f
#define CAP 64
#define PBUF 256
#define K2 (20.0f * 1.442695040888963f)   // INV_TAU * log2(e)

typedef __attribute__((ext_vector_type(4))) float f32x4;
typedef __attribute__((ext_vector_type(8))) short bf16x8_t;

#define GLOAD16(gp, lp) \
    __builtin_amdgcn_global_load_lds((const __attribute__((address_space(1))) void*)(gp), \
                                     (__attribute__((address_space(3))) void*)(lp), 16, 0, 0)

__device__ __forceinline__ unsigned short f2bf(float f) {
    union { float f; unsigned u; } v; v.f = f;
    unsigned r = v.u + 0x7FFFu + ((v.u >> 16) & 1u);
    return (unsigned short)(r >> 16);
}

// Fused: L2-normalize every row of que/sen/sec into bf16. Wave per row.
__global__ void norm_all(const float* __restrict__ que, const float* __restrict__ sen,
                         const float* __restrict__ sec,
                         unsigned short* __restrict__ queb, unsigned short* __restrict__ senb,
                         unsigned short* __restrict__ secb, int Q, int N, int S) {
    int r = blockIdx.x * 4 + (threadIdx.x >> 6);
    int lane = threadIdx.x & 63;
    if (r >= Q + N + S) return;
    const float* src; unsigned short* dst; int row;
    if (r < Q) { src = que; dst = queb; row = r; }
    else if (r < Q + N) { src = sen; dst = senb; row = r - Q; }
    else { src = sec; dst = secb; row = r - Q - N; }
    const float4* p = (const float4*)(src + (size_t)row * D);
    float4 v = p[lane];
    float ss = v.x * v.x + v.y * v.y + v.z * v.z + v.w * v.w;
    #pragma unroll
    for (int m = 1; m < 64; m <<= 1) ss += __shfl_xor(ss, m);
    float rn = rsqrtf(ss);
    ushort4 o;
    o.x = f2bf(v.x * rn); o.y = f2bf(v.y * rn); o.z = f2bf(v.z * rn); o.w = f2bf(v.w * rn);
    *(ushort4*)(dst + (size_t)row * D + lane * 4) = o;
}

// Mega kernel, 512 threads (8 waves), 1-D grid = 16 SQ blocks + 1024 QS blocks.
// QS: 256(q) x 256(n) tile, BK=32 double-buffered 2-phase (R8's proven step),
// wave grid 2(q) x 4(n), per-wave output 128x64 (acc[8][4] = 128 VGPR).
// Chunk swizzle c ^= (r>>1)&3 on source + read (xor term == (cl>>1)&3 for all frags;
// measured 0-conflict in R6/R8). Staged traffic halves vs 128^2: 268 MB total.
__global__ __launch_bounds__(512, 2)
void qs_sq(const unsigned short* __restrict__ queb, const unsigned short* __restrict__ senb,
           const unsigned short* __restrict__ secb,
           const int* __restrict__ pidq, const int* __restrict__ pidn,
           const int* __restrict__ sidx, int Q,
           float* __restrict__ partial, int* __restrict__ cnt, float* __restrict__ pos_s,
           float* __restrict__ sq_all, float* __restrict__ sq_pos, int* __restrict__ sq_m,
           float* __restrict__ simq) {
    __shared__ unsigned short As[2][256 * 32];
    __shared__ unsigned short Bs[2][256 * 32];
    __shared__ int pqs[256];
    __shared__ int pns[256];
    __shared__ float sums[4][256];
    __shared__ int lcnt;
    __shared__ int lq[PBUF];
    __shared__ float lsv[PBUF];

    const int tid = threadIdx.x;
    const int lane = tid & 63;
    const int cl = lane & 15;
    const int g = lane >> 4;
    const int wid = tid >> 6;
    const int bid = blockIdx.x;
    const int nsq = Q >> 8;   // 16 SQ blocks

    if (bid < nsq) {
        // ---------------- SQ path: 64 sections x 256 questions ----------------
        const int q0 = bid * 256;
        const int qw = q0 + wid * 32;
        f32x4 acc[4][2];
        #pragma unroll
        for (int si = 0; si < 4; ++si)
            #pragma unroll
            for (int qi = 0; qi < 2; ++qi)
                acc[si][qi] = (f32x4){0.f, 0.f, 0.f, 0.f};
        const unsigned short* abase = secb + (size_t)cl * D + g * 8;
        const unsigned short* bbase = queb + (size_t)(qw + cl) * D + g * 8;
        #pragma unroll
        for (int kk = 0; kk < 8; ++kk) {
            const int k0 = kk * 32;
            bf16x8_t af[4], bq[2];
            #pragma unroll
            for (int si = 0; si < 4; ++si)
                af[si] = *(const bf16x8_t*)(abase + si * 16 * D + k0);
            #pragma unroll
            for (int qi = 0; qi < 2; ++qi)
                bq[qi] = *(const bf16x8_t*)(bbase + qi * 16 * D + k0);
            #pragma unroll
            for (int si = 0; si < 4; ++si)
                #pragma unroll
                for (int qi = 0; qi < 2; ++qi)
                    acc[si][qi] = __builtin_amdgcn_mfma_f32_16x16x32_bf16(af[si], bq[qi], acc[si][qi], 0, 0, 0);
        }
        int sidxv[2];
        sidxv[0] = sidx[qw + cl];
        sidxv[1] = sidx[qw + 16 + cl];
        #pragma unroll
        for (int si = 0; si < 4; ++si) {
            float pa[4] = {0.f, 0.f, 0.f, 0.f};
            #pragma unroll
            for (int qi = 0; qi < 2; ++qi) {
                #pragma unroll
                for (int j = 0; j < 4; ++j) {
                    int srow = si * 16 + g * 4 + j;
                    float sv = acc[si][qi][j] * INV_TAU;
                    float e = __expf(sv);
                    pa[j] += e;
                    if (sidxv[qi] == srow) {
                        int q = qw + qi * 16 + cl;
                        simq[q] = sv;
                        atomicAdd(&sq_pos[srow], e);
                        atomicAdd(&sq_m[srow], 1);
                    }
                }
            }
            #pragma unroll
            for (int j = 0; j < 4; ++j) {
                float a = pa[j];
                #pragma unroll
                for (int msk = 1; msk < 16; msk <<= 1) a += __shfl_xor(a, msk);
                if (cl == 0) atomicAdd(&sq_all[si * 16 + g * 4 + j], a);
            }
        }
        return;
    }

    // ---------------- QS path: one 256x256 tile-pair ----------------
    const int qbid = bid - nsq;
    const int qt = qbid >> 6;       // 16 q-tiles (consecutive blocks share A range)
    const int nt = qbid & 63;       // 64 n-tiles
    const int wrow = wid >> 2;      // 0..1
    const int wcol = wid & 3;       // 0..3
    const int q0 = qt * 256;
    const int n0 = nt * 256;

    if (tid < 256) pqs[tid] = pidq[q0 + tid];
    else           pns[tid - 256] = pidn[n0 + tid - 256];
    if (tid == 0) lcnt = 0;
    __syncthreads();   // pid visible + vmcnt drained before counted waits

    // Staging: per buffer 256 rows x 32 el = 1024 16B-chunks per matrix; thread i
    // covers chunks {tid, 512+tid}. r = tid>>2 (+128), c = tid&3; swz xor = (tid>>3)&3
    // for both (128 ≡ 0 mod stride). Source pre-swizzled, LDS dest linear.
    const int swz = (((tid & 3) ^ ((tid >> 3) & 3)) << 3);
    const unsigned short* qa0 = queb + (size_t)(q0 + (tid >> 2)) * D + swz;
    const unsigned short* sb0 = senb + (size_t)(n0 + (tid >> 2)) * D + swz;
    const int ld0 = wid * 512;             // wave-uniform LDS element base (inst 0)
    const int ld1 = 4096 + wid * 512;      // inst 1

#define STAGE(buf, k0) do { \
    GLOAD16(qa0 + (k0), &As[buf][ld0]); \
    GLOAD16(qa0 + 128 * D + (k0), &As[buf][ld1]); \
    GLOAD16(sb0 + (k0), &Bs[buf][ld0]); \
    GLOAD16(sb0 + 128 * D + (k0), &Bs[buf][ld1]); \
} while (0)

    f32x4 acc[8][4];
    #pragma unroll
    for (int m = 0; m < 8; ++m)
        #pragma unroll
        for (int n = 0; n < 4; ++n)
            acc[m][n] = (f32x4){0.f, 0.f, 0.f, 0.f};

    // Read offsets: want global chunk (r, g); stored at c = g ^ ((r>>1)&3), and
    // (r>>1)&3 == (cl>>1)&3 for every fragment base (bases are multiples of 16).
    const int xorv = (g ^ ((cl >> 1) & 3)) << 3;
    int offA[8], offB[4];
    #pragma unroll
    for (int m = 0; m < 8; ++m)
        offA[m] = (wrow * 128 + m * 16 + cl) * 32 + xorv;
    #pragma unroll
    for (int n = 0; n < 4; ++n)
        offB[n] = (wcol * 64 + n * 16 + cl) * 32 + xorv;

    STAGE(0, 0);
    #pragma unroll
    for (int ks = 0; ks < 8; ++ks) {
        const int cur = ks & 1;
        if (ks < 7) {
            STAGE(cur ^ 1, (ks + 1) * 32);
            asm volatile("s_waitcnt vmcnt(4)" ::: "memory");
        } else {
            asm volatile("s_waitcnt vmcnt(0)" ::: "memory");
        }
        __builtin_amdgcn_s_barrier();
        bf16x8_t af[8], bg[4];
        #pragma unroll
        for (int m = 0; m < 8; ++m) af[m] = *(const bf16x8_t*)&As[cur][offA[m]];
        #pragma unroll
        for (int n = 0; n < 4; ++n) bg[n] = *(const bf16x8_t*)&Bs[cur][offB[n]];
        #pragma unroll
        for (int m = 0; m < 8; ++m)
            #pragma unroll
            for (int n = 0; n < 4; ++n)
                acc[m][n] = __builtin_amdgcn_mfma_f32_16x16x32_bf16(af[m], bg[n], acc[m][n], 0, 0, 0);
        if (ks < 7) __builtin_amdgcn_s_barrier();
    }
#undef STAGE

    // Epilogue: exp2 + per-row sums + LDS positive capture.
    float se[32];
    #pragma unroll
    for (int i = 0; i < 32; ++i) se[i] = 0.f;
    #pragma unroll
    for (int m = 0; m < 8; ++m) {
        int pqr[4];
        #pragma unroll
        for (int j = 0; j < 4; ++j) pqr[j] = pqs[wrow * 128 + m * 16 + g * 4 + j];
        #pragma unroll
        for (int n = 0; n < 4; ++n) {
            const int pcol = pns[wcol * 64 + n * 16 + cl];
            #pragma unroll
            for (int j = 0; j < 4; ++j) {
                float e = __builtin_amdgcn_exp2f(acc[m][n][j] * K2);
                se[m * 4 + j] += e;
                if (pqr[j] == pcol) {
                    int li = atomicAdd(&lcnt, 1);
                    if (li < PBUF) {
                        lq[li] = q0 + wrow * 128 + m * 16 + g * 4 + j;
                        lsv[li] = acc[m][n][j] * INV_TAU;
                    }
                }
            }
        }
    }
    // Per-wave n-reduce (over cl), write into sums[wcol][row]; rows disjoint per wrow.
    #pragma unroll
    for (int i = 0; i < 32; ++i) {
        float a = se[i];
        #pragma unroll
        for (int msk = 1; msk < 16; msk <<= 1) a += __shfl_xor(a, msk);
        if (cl == 0)
            sums[wcol][wrow * 128 + (i >> 2) * 16 + g * 4 + (i & 3)] = a;
    }
    __syncthreads();
    if (tid < 256)
        partial[(size_t)nt * Q + q0 + tid] =
            sums[0][tid] + sums[1][tid] + sums[2][tid] + sums[3][tid];
    int nc = lcnt < PBUF ? lcnt : PBUF;
    for (int i = tid; i < nc; i += 512) {
        int q = lq[i];
        int idx = atomicAdd(&cnt[q], 1);
        if (idx < CAP) pos_s[(size_t)q * CAP + idx] = lsv[i];
    }
}

// Finish: wave per question. Reduces row partials, computes g + QS terms + SQ term.
__global__ __launch_bounds__(256)
void finish(const float* __restrict__ partial, int NSLICE,
            const int* __restrict__ cnt, const float* __restrict__ pos_s,
            const int* __restrict__ sidx, const float* __restrict__ simq,
            const float* __restrict__ sq_all, const float* __restrict__ sq_pos,
            const int* __restrict__ sq_m,
            const int* __restrict__ npp, int Qn, int Ntot,
            float* __restrict__ bpart) {
    __shared__ float fred[4][4];
    const int tid = threadIdx.x, lane = tid & 63, wid = tid >> 6;
    const int q = blockIdx.x * 4 + wid;

    float Sa = 0.f;
    for (int nb = lane; nb < NSLICE; nb += 64) Sa += partial[(size_t)nb * Qn + q];
    #pragma unroll
    for (int m = 1; m < 64; m <<= 1) Sa += __shfl_xor(Sa, m);

    int M = cnt[q];
    int mc = M < CAP ? M : CAP;
    float s = 0.f, e = 0.f;
    if (lane < mc) { s = pos_s[(size_t)q * CAP + lane]; e = __expf(s); }
    float Sp = e;
    #pragma unroll
    for (int m = 1; m < 64; m <<= 1) Sp += __shfl_xor(Sp, m);

    int Nn = Ntot - M;
    int P = npp[0];
    float eta_p = 1.0f / (float)(P > 1 ? P : 1);
    float eta_m = 1.0f - eta_p;
    float Mf = (float)(M > 1 ? M : 1);
    float Nnf = (float)(Nn > 1 ? Nn : 1);
    float gg = fmaxf(((Sa - Sp) / Nnf - eta_p * Sp / Mf) / eta_m, __expf(-INV_TAU));
    float c = (float)Nn * gg;

    float contrib = (lane < mc) ? (s - __logf(e + c)) : 0.f;
    #pragma unroll
    for (int m = 1; m < 64; m <<= 1) contrib += __shfl_xor(contrib, m);

    if (lane == 0) {
        float qs_num = 0.f, qs_cnt = 0.f, sq_num = 0.f, sq_cnt = 0.f;
        if (M > 0 && Nn > 0) { qs_num = contrib; qs_cnt = (float)M; }
        int sct = sidx[q];
        int Mq = sq_m[sct];
        if (Mq > 0 && (Qn - Mq) > 0) {
            float sv = simq[q];
            float sumneg = sq_all[sct] - sq_pos[sct];
            sq_num = sv - __logf(__expf(sv) + sumneg);
            sq_cnt = 1.f;
        }
        fred[wid][0] = qs_num; fred[wid][1] = qs_cnt;
        fred[wid][2] = sq_num; fred[wid][3] = sq_cnt;
    }
    __syncthreads();
    if (tid < 4) {
        float v = fred[0][tid] + fred[1][tid] + fred[2][tid] + fred[3][tid];
        bpart[(size_t)blockIdx.x * 4 + tid] = v;
    }
}

__global__ void combine2(const float* __restrict__ bpart, int nblk, float* __restrict__ out) {
    __shared__ float r2[4][4];
    const int tid = threadIdx.x, lane = tid & 63, wid = tid >> 6;
    float v[4] = {0.f, 0.f, 0.f, 0.f};
    for (int i = tid; i < nblk; i += 256) {
        #pragma unroll
        for (int c2 = 0; c2 < 4; ++c2) v[c2] += bpart[(size_t)i * 4 + c2];
    }
    #pragma unroll
    for (int m = 1; m < 64; m <<= 1)
        #pragma unroll
        for (int c2 = 0; c2 < 4; ++c2) v[c2] += __shfl_xor(v[c2], m);
    if (lane == 0) {
        #pragma unroll
        for (int c2 = 0; c2 < 4; ++c2) r2[wid][c2] = v[c2];
    }
    __syncthreads();
    if (tid == 0) {
        float qs_num = r2[0][0] + r2[1][0] + r2[2][0] + r2[3][0];
        float qs_cnt = r2[0][1] + r2[1][1] + r2[2][1] + r2[3][1];
        float sq_num = r2[0][2] + r2[1][2] + r2[2][2] + r2[3][2];
        float sq_cnt = r2[0][3] + r2[1][3] + r2[2][3] + r2[3][3];
        float qs = qs_cnt > 0.f ? -qs_num / qs_cnt : 0.f;
        float sq = sq_cnt > 0.f ? -sq_num / sq_cnt : 0.f;
        out[0] = qs + sq;
    }
}

extern "C" void kernel_launch(void* const* d_in, const int* in_sizes, int n_in,
                              void* d_out, int out_size, void* d_ws, size_t ws_size,
                              hipStream_t stream) {
    const float* sec = (const float*)d_in[1];
    const float* que = (const float*)d_in[2];
    const float* sen = (const float*)d_in[3];
    const int* pidq = (const int*)d_in[4];
    const int* sidx = (const int*)d_in[5];
    const int* pidn = (const int*)d_in[6];
    const int* npp = (const int*)d_in[7];
    const int S = in_sizes[1] / D;
    const int Q = in_sizes[2] / D;
    const int N = in_sizes[3] / D;
    const int NSLICE = N / 256;   // 64
    const int FBLK = Q / 4;

    char* p = (char*)d_ws;
    unsigned short* queb = (unsigned short*)p; p += (size_t)Q * D * 2;
    unsigned short* senb = (unsigned short*)p; p += (size_t)N * D * 2;
    unsigned short* secb = (unsigned short*)p; p += (size_t)S * D * 2;
    float* simq = (float*)p; p += (size_t)Q * 4;
    float* pos_s = (float*)p; p += (size_t)Q * CAP * 4;
    float* partial = (float*)p; p += (size_t)NSLICE * Q * 4;
    float* bpart = (float*)p; p += (size_t)FBLK * 4 * 4;
    char* z0 = p;
    int* cnt = (int*)p; p += (size_t)Q * 4;
    float* sq_all = (float*)p; p += (size_t)S * 4;
    float* sq_pos = (float*)p; p += (size_t)S * 4;
    int* sq_m = (int*)p; p += (size_t)S * 4;
    size_t zbytes = (size_t)(p - z0);

    hipMemsetAsync(z0, 0, zbytes, stream);
    norm_all<<<(Q + N + S + 3) / 4, 256, 0, stream>>>(que, sen, sec, queb, senb, secb, Q, N, S);
    // 16 SQ blocks + (Q/256)*(N/256) = 1024 QS blocks, 512 threads each.
    qs_sq<<<Q / 256 + (Q / 256) * (N / 256), 512, 0, stream>>>(queb, senb, secb, pidq, pidn,
                                                               sidx, Q, partial, cnt, pos_s,
                                                               sq_all, sq_pos, sq_m, simq);
    finish<<<FBLK, 256, 0, stream>>>(partial, NSLICE, cnt, pos_s, sidx, simq,
                                     sq_all, sq_pos, sq_m, npp, Q, N, bpart);
    combine2<<<1, 256, 0, stream>>>(bpart, FBLK, (float*)d_out);
}

// Round 12
// 103.705 us; speedup vs baseline: 1.1646x; 1.1646x over previous
//
#include <hip/hip_runtime.h>
#include <hip/hip_bf16.h>
#include <math.h>

#define D 256
#define INV_TAU 20.0f
#define CAP 64
#define PBUF 128
#define K2 (20.0f * 1.442695040888963f)   // INV_TAU * log2(e)

typedef __attribute__((ext_vector_type(4))) float f32x4;
typedef __attribute__((ext_vector_type(8))) short bf16x8_t;

#define GLOAD16(gp, lp) \
    __builtin_amdgcn_global_load_lds((const __attribute__((address_space(1))) void*)(gp), \
                                     (__attribute__((address_space(3))) void*)(lp), 16, 0, 0)

__device__ __forceinline__ unsigned short f2bf(float f) {
    union { float f; unsigned u; } v; v.f = f;
    unsigned r = v.u + 0x7FFFu + ((v.u >> 16) & 1u);
    return (unsigned short)(r >> 16);
}

// Fused: L2-normalize every row of que/sen/sec into bf16. Wave per row.
__global__ void norm_all(const float* __restrict__ que, const float* __restrict__ sen,
                         const float* __restrict__ sec,
                         unsigned short* __restrict__ queb, unsigned short* __restrict__ senb,
                         unsigned short* __restrict__ secb, int Q, int N, int S) {
    int r = blockIdx.x * 4 + (threadIdx.x >> 6);
    int lane = threadIdx.x & 63;
    if (r >= Q + N + S) return;
    const float* src; unsigned short* dst; int row;
    if (r < Q) { src = que; dst = queb; row = r; }
    else if (r < Q + N) { src = sen; dst = senb; row = r - Q; }
    else { src = sec; dst = secb; row = r - Q - N; }
    const float4* p = (const float4*)(src + (size_t)row * D);
    float4 v = p[lane];
    float ss = v.x * v.x + v.y * v.y + v.z * v.z + v.w * v.w;
    #pragma unroll
    for (int m = 1; m < 64; m <<= 1) ss += __shfl_xor(ss, m);
    float rn = rsqrtf(ss);
    ushort4 o;
    o.x = f2bf(v.x * rn); o.y = f2bf(v.y * rn); o.z = f2bf(v.z * rn); o.w = f2bf(v.w * rn);
    *(ushort4*)(dst + (size_t)row * D + lane * 4) = o;
}

// Mega kernel, 1-D grid = 32 SQ blocks + 4096 QS blocks, 256 threads.
// QS: m97-shape GEMM — 128x128 tile, BK=64, SINGLE LDS buffer, plain __syncthreads
// (full drain; cross-wave TLP at 4 blocks/CU hides it — m114/m97 measured pattern).
// Per K-step: 8 global_load_lds + 16 ds_read_b128 + 32 MFMA per wave.
// Swizzle for 128B rows: chunk col ^= row&7 on SOURCE + READ, LDS linear (rule #21).
__global__ __launch_bounds__(256, 4)
void qs_sq(const unsigned short* __restrict__ queb, const unsigned short* __restrict__ senb,
           const unsigned short* __restrict__ secb,
           const int* __restrict__ pidq, const int* __restrict__ pidn,
           const int* __restrict__ sidx, int Q,
           float* __restrict__ partial, int* __restrict__ cnt, float* __restrict__ pos_s,
           float* __restrict__ sq_all, float* __restrict__ sq_pos, int* __restrict__ sq_m,
           float* __restrict__ simq) {
    __shared__ unsigned short As[128 * 64];
    __shared__ unsigned short Bs[128 * 64];
    __shared__ int pqs[128];
    __shared__ int pns[128];
    __shared__ float sums[2][128];
    __shared__ int lcnt;
    __shared__ int lq[PBUF];
    __shared__ float lsv[PBUF];

    const int tid = threadIdx.x;
    const int lane = tid & 63;
    const int cl = lane & 15;
    const int g = lane >> 4;
    const int wid = tid >> 6;
    const int bid = blockIdx.x;
    const int nsq = Q >> 7;   // 32 SQ blocks

    if (bid < nsq) {
        // ---------------- SQ path: 64 sections x 128 questions ----------------
        const int q0 = bid * 128;
        const int qw = q0 + wid * 32;
        f32x4 acc[4][2];
        #pragma unroll
        for (int si = 0; si < 4; ++si)
            #pragma unroll
            for (int qi = 0; qi < 2; ++qi)
                acc[si][qi] = (f32x4){0.f, 0.f, 0.f, 0.f};
        const unsigned short* abase = secb + (size_t)cl * D + g * 8;
        const unsigned short* bbase = queb + (size_t)(qw + cl) * D + g * 8;
        #pragma unroll
        for (int kk = 0; kk < 8; ++kk) {
            const int k0 = kk * 32;
            bf16x8_t af[4], bq[2];
            #pragma unroll
            for (int si = 0; si < 4; ++si)
                af[si] = *(const bf16x8_t*)(abase + si * 16 * D + k0);
            #pragma unroll
            for (int qi = 0; qi < 2; ++qi)
                bq[qi] = *(const bf16x8_t*)(bbase + qi * 16 * D + k0);
            #pragma unroll
            for (int si = 0; si < 4; ++si)
                #pragma unroll
                for (int qi = 0; qi < 2; ++qi)
                    acc[si][qi] = __builtin_amdgcn_mfma_f32_16x16x32_bf16(af[si], bq[qi], acc[si][qi], 0, 0, 0);
        }
        int sidxv[2];
        sidxv[0] = sidx[qw + cl];
        sidxv[1] = sidx[qw + 16 + cl];
        #pragma unroll
        for (int si = 0; si < 4; ++si) {
            float pa[4] = {0.f, 0.f, 0.f, 0.f};
            #pragma unroll
            for (int qi = 0; qi < 2; ++qi) {
                #pragma unroll
                for (int j = 0; j < 4; ++j) {
                    int srow = si * 16 + g * 4 + j;
                    float sv = acc[si][qi][j] * INV_TAU;
                    float e = __expf(sv);
                    pa[j] += e;
                    if (sidxv[qi] == srow) {
                        int q = qw + qi * 16 + cl;
                        simq[q] = sv;
                        atomicAdd(&sq_pos[srow], e);
                        atomicAdd(&sq_m[srow], 1);
                    }
                }
            }
            #pragma unroll
            for (int j = 0; j < 4; ++j) {
                float a = pa[j];
                #pragma unroll
                for (int msk = 1; msk < 16; msk <<= 1) a += __shfl_xor(a, msk);
                if (cl == 0) atomicAdd(&sq_all[si * 16 + g * 4 + j], a);
            }
        }
        return;
    }

    // ---------------- QS path ----------------
    const int qbid = bid - nsq;
    const int qt = qbid & 31;       // 32 consecutive blocks share the same n-tile
    const int nt = qbid >> 5;       // 128 n-tiles
    const int wr = wid >> 1, wc = wid & 1;
    const int q0 = qt * 128;
    const int n0 = nt * 128;

    if (tid < 128) pqs[tid] = pidq[q0 + tid];
    else           pns[tid - 128] = pidn[n0 + tid - 128];
    if (tid == 0) lcnt = 0;

    // Staging: tile = 128 rows x 64 el = 1024 16B-chunks per matrix; thread covers
    // cid = j*256 + tid (j=0..3): row = j*32 + (tid>>3), ch = tid&7.
    // Source chunk col = ch ^ (row&7); row&7 = (tid>>3)&7 (j*32 preserves it).
    // LDS dest linear in cid; wave-uniform base per (j, wid).
    const int srow = tid >> 3;
    const int sch = (tid & 7) ^ (srow & 7);
    const unsigned short* qa = queb + (size_t)(q0 + srow) * D + sch * 8;
    const unsigned short* sb = senb + (size_t)(n0 + srow) * D + sch * 8;

#define STAGE(k0) do { \
    _Pragma("unroll") \
    for (int j_ = 0; j_ < 4; ++j_) { \
        GLOAD16(qa + (k0) + j_ * 32 * D, &As[j_ * 2048 + wid * 512]); \
        GLOAD16(sb + (k0) + j_ * 32 * D, &Bs[j_ * 2048 + wid * 512]); \
    } } while (0)

    f32x4 acc[4][4];
    #pragma unroll
    for (int m = 0; m < 4; ++m)
        #pragma unroll
        for (int n = 0; n < 4; ++n)
            acc[m][n] = (f32x4){0.f, 0.f, 0.f, 0.f};

    // Fragment read offsets (kk=0): want global chunk (r, g); stored at g ^ (r&7),
    // r&7 = cl&7. kk=1 flips chunk bit 2 -> element-offset bit 5 (XOR 32).
    int offA0[4], offB0[4];
    #pragma unroll
    for (int m = 0; m < 4; ++m) {
        int r = wr * 64 + m * 16 + cl;
        offA0[m] = r * 64 + ((g ^ (cl & 7)) << 3);
    }
    #pragma unroll
    for (int n = 0; n < 4; ++n) {
        int r = wc * 64 + n * 16 + cl;
        offB0[n] = r * 64 + ((g ^ (cl & 7)) << 3);
    }

    STAGE(0);
    #pragma unroll
    for (int ks = 0; ks < 4; ++ks) {
        __syncthreads();   // drains vmcnt (own loads) + rendezvous: LDS tile ready
        #pragma unroll
        for (int kk = 0; kk < 2; ++kk) {
            const int kx = kk << 5;
            bf16x8_t af[4], bg[4];
            #pragma unroll
            for (int m = 0; m < 4; ++m) af[m] = *(const bf16x8_t*)&As[offA0[m] ^ kx];
            #pragma unroll
            for (int n = 0; n < 4; ++n) bg[n] = *(const bf16x8_t*)&Bs[offB0[n] ^ kx];
            #pragma unroll
            for (int m = 0; m < 4; ++m)
                #pragma unroll
                for (int n = 0; n < 4; ++n)
                    acc[m][n] = __builtin_amdgcn_mfma_f32_16x16x32_bf16(af[m], bg[n], acc[m][n], 0, 0, 0);
        }
        if (ks < 3) {
            __syncthreads();          // all reads of this tile done before overwrite
            STAGE((ks + 1) * 64);
        }
    }
#undef STAGE

    // Epilogue: exp2 + per-row sums (block-local) + LDS positive capture.
    #pragma unroll
    for (int m = 0; m < 4; ++m) {
        float se[4] = {0.f, 0.f, 0.f, 0.f};
        int pqr[4];
        #pragma unroll
        for (int j = 0; j < 4; ++j) pqr[j] = pqs[wr * 64 + m * 16 + g * 4 + j];
        #pragma unroll
        for (int n = 0; n < 4; ++n) {
            const int pcol = pns[wc * 64 + n * 16 + cl];
            #pragma unroll
            for (int j = 0; j < 4; ++j) {
                float e = __builtin_amdgcn_exp2f(acc[m][n][j] * K2);
                se[j] += e;
                if (pqr[j] == pcol) {
                    int li = atomicAdd(&lcnt, 1);
                    if (li < PBUF) {
                        lq[li] = q0 + wr * 64 + m * 16 + g * 4 + j;
                        lsv[li] = acc[m][n][j] * INV_TAU;
                    }
                }
            }
        }
        #pragma unroll
        for (int j = 0; j < 4; ++j) {
            float a = se[j];
            #pragma unroll
            for (int msk = 1; msk < 16; msk <<= 1) a += __shfl_xor(a, msk);
            if (cl == 0) sums[wc][wr * 64 + m * 16 + g * 4 + j] = a;
        }
    }
    __syncthreads();
    if (tid < 128)
        partial[(size_t)nt * Q + q0 + tid] = sums[0][tid] + sums[1][tid];
    int nc = lcnt < PBUF ? lcnt : PBUF;
    for (int i = tid; i < nc; i += 256) {
        int q = lq[i];
        int idx = atomicAdd(&cnt[q], 1);
        if (idx < CAP) pos_s[(size_t)q * CAP + idx] = lsv[i];
    }
}

// Finish: wave per question. Reduces row partials, computes g + QS terms + SQ term.
__global__ __launch_bounds__(256)
void finish(const float* __restrict__ partial, int NSLICE,
            const int* __restrict__ cnt, const float* __restrict__ pos_s,
            const int* __restrict__ sidx, const float* __restrict__ simq,
            const float* __restrict__ sq_all, const float* __restrict__ sq_pos,
            const int* __restrict__ sq_m,
            const int* __restrict__ npp, int Qn, int Ntot,
            float* __restrict__ bpart) {
    __shared__ float fred[4][4];
    const int tid = threadIdx.x, lane = tid & 63, wid = tid >> 6;
    const int q = blockIdx.x * 4 + wid;

    float Sa = 0.f;
    for (int nb = lane; nb < NSLICE; nb += 64) Sa += partial[(size_t)nb * Qn + q];
    #pragma unroll
    for (int m = 1; m < 64; m <<= 1) Sa += __shfl_xor(Sa, m);

    int M = cnt[q];
    int mc = M < CAP ? M : CAP;
    float s = 0.f, e = 0.f;
    if (lane < mc) { s = pos_s[(size_t)q * CAP + lane]; e = __expf(s); }
    float Sp = e;
    #pragma unroll
    for (int m = 1; m < 64; m <<= 1) Sp += __shfl_xor(Sp, m);

    int Nn = Ntot - M;
    int P = npp[0];
    float eta_p = 1.0f / (float)(P > 1 ? P : 1);
    float eta_m = 1.0f - eta_p;
    float Mf = (float)(M > 1 ? M : 1);
    float Nnf = (float)(Nn > 1 ? Nn : 1);
    float gg = fmaxf(((Sa - Sp) / Nnf - eta_p * Sp / Mf) / eta_m, __expf(-INV_TAU));
    float c = (float)Nn * gg;

    float contrib = (lane < mc) ? (s - __logf(e + c)) : 0.f;
    #pragma unroll
    for (int m = 1; m < 64; m <<= 1) contrib += __shfl_xor(contrib, m);

    if (lane == 0) {
        float qs_num = 0.f, qs_cnt = 0.f, sq_num = 0.f, sq_cnt = 0.f;
        if (M > 0 && Nn > 0) { qs_num = contrib; qs_cnt = (float)M; }
        int sct = sidx[q];
        int Mq = sq_m[sct];
        if (Mq > 0 && (Qn - Mq) > 0) {
            float sv = simq[q];
            float sumneg = sq_all[sct] - sq_pos[sct];
            sq_num = sv - __logf(__expf(sv) + sumneg);
            sq_cnt = 1.f;
        }
        fred[wid][0] = qs_num; fred[wid][1] = qs_cnt;
        fred[wid][2] = sq_num; fred[wid][3] = sq_cnt;
    }
    __syncthreads();
    if (tid < 4) {
        float v = fred[0][tid] + fred[1][tid] + fred[2][tid] + fred[3][tid];
        bpart[(size_t)blockIdx.x * 4 + tid] = v;
    }
}

__global__ void combine2(const float* __restrict__ bpart, int nblk, float* __restrict__ out) {
    __shared__ float r2[4][4];
    const int tid = threadIdx.x, lane = tid & 63, wid = tid >> 6;
    float v[4] = {0.f, 0.f, 0.f, 0.f};
    for (int i = tid; i < nblk; i += 256) {
        #pragma unroll
        for (int c2 = 0; c2 < 4; ++c2) v[c2] += bpart[(size_t)i * 4 + c2];
    }
    #pragma unroll
    for (int m = 1; m < 64; m <<= 1)
        #pragma unroll
        for (int c2 = 0; c2 < 4; ++c2) v[c2] += __shfl_xor(v[c2], m);
    if (lane == 0) {
        #pragma unroll
        for (int c2 = 0; c2 < 4; ++c2) r2[wid][c2] = v[c2];
    }
    __syncthreads();
    if (tid == 0) {
        float qs_num = r2[0][0] + r2[1][0] + r2[2][0] + r2[3][0];
        float qs_cnt = r2[0][1] + r2[1][1] + r2[2][1] + r2[3][1];
        float sq_num = r2[0][2] + r2[1][2] + r2[2][2] + r2[3][2];
        float sq_cnt = r2[0][3] + r2[1][3] + r2[2][3] + r2[3][3];
        float qs = qs_cnt > 0.f ? -qs_num / qs_cnt : 0.f;
        float sq = sq_cnt > 0.f ? -sq_num / sq_cnt : 0.f;
        out[0] = qs + sq;
    }
}

extern "C" void kernel_launch(void* const* d_in, const int* in_sizes, int n_in,
                              void* d_out, int out_size, void* d_ws, size_t ws_size,
                              hipStream_t stream) {
    const float* sec = (const float*)d_in[1];
    const float* que = (const float*)d_in[2];
    const float* sen = (const float*)d_in[3];
    const int* pidq = (const int*)d_in[4];
    const int* sidx = (const int*)d_in[5];
    const int* pidn = (const int*)d_in[6];
    const int* npp = (const int*)d_in[7];
    const int S = in_sizes[1] / D;
    const int Q = in_sizes[2] / D;
    const int N = in_sizes[3] / D;
    const int NB = N / 128;
    const int FBLK = Q / 4;

    char* p = (char*)d_ws;
    unsigned short* queb = (unsigned short*)p; p += (size_t)Q * D * 2;
    unsigned short* senb = (unsigned short*)p; p += (size_t)N * D * 2;
    unsigned short* secb = (unsigned short*)p; p += (size_t)S * D * 2;
    float* simq = (float*)p; p += (size_t)Q * 4;
    float* pos_s = (float*)p; p += (size_t)Q * CAP * 4;
    float* partial = (float*)p; p += (size_t)NB * Q * 4;
    float* bpart = (float*)p; p += (size_t)FBLK * 4 * 4;
    char* z0 = p;
    int* cnt = (int*)p; p += (size_t)Q * 4;
    float* sq_all = (float*)p; p += (size_t)S * 4;
    float* sq_pos = (float*)p; p += (size_t)S * 4;
    int* sq_m = (int*)p; p += (size_t)S * 4;
    size_t zbytes = (size_t)(p - z0);

    hipMemsetAsync(z0, 0, zbytes, stream);
    norm_all<<<(Q + N + S + 3) / 4, 256, 0, stream>>>(que, sen, sec, queb, senb, secb, Q, N, S);
    qs_sq<<<Q / 128 + (Q / 128) * NB, 256, 0, stream>>>(queb, senb, secb, pidq, pidn, sidx, Q,
                                                        partial, cnt, pos_s,
                                                        sq_all, sq_pos, sq_m, simq);
    finish<<<FBLK, 256, 0, stream>>>(partial, NB, cnt, pos_s, sidx, simq,
                                     sq_all, sq_pos, sq_m, npp, Q, N, bpart);
    combine2<<<1, 256, 0, stream>>>(bpart, FBLK, (float*)d_out);
}